// Round 3
// baseline (7035152.344 us; speedup 1.0000x reference)
//
#include <hip/hip_runtime.h>

// YOLO-style loss: pred/target (bs, 7, 7, 30) fp32 -> scalar.
// S=7, B=2 boxes (5 ch each), C=20 classes. Memory-bound streaming reduction.
//
// v4: read-once + coalesced + high occupancy.
//  - One fully-coalesced float4 sweep over the block's 7680-float range of
//    both tensors (each byte read EXACTLY once -> restores the ~50% L3
//    residency that v3's double-read destroyed, FETCH 357->~190MB).
//  - Class-channel (ch>=10) squared diffs are consumed inline during the
//    sweep into a fully-unrolled register array; per-cell obj weights are
//    applied after the barrier via a 1KB LDS obj table (v3's deferral).
//  - Only box channels (ch 0..9, incl. conf 4/9) are staged to LDS, padded
//    stride 11 (gcd(11,32)=1 -> conflict-free 2-way gather reads).
//    LDS: 2*11KB + 1KB = 23.6KB -> 6 blocks/CU (~75% occupancy) vs v1's
//    60.5KB -> 2 blocks/CU (21%), which was v1's latency-hiding wall.
//  - Per-cell box/IoU/conf math from LDS, identical arithmetic to v2/v3
//    (absmax 0.0 on both).
// Pass 2: single block reduces per-block partials -> out[0]. Deterministic.
// Fallback (ws too small): zero-init + one atomicAdd per block.

#define CH 30
#define PAD 11
#define SDIV 7.0f

template <bool USE_ATOMIC>
__global__ __launch_bounds__(256) void yolo_loss_pass1(
    const float* __restrict__ pred, const float* __restrict__ tgt,
    float* __restrict__ dst, long long n_cells, float scale)
{
    __shared__ float sp_box[256 * PAD];   // pred ch0..9, pad 11
    __shared__ float st_box[256 * PAD];   // tgt  ch0..9, pad 11
    __shared__ float s_obj[256];
    __shared__ float wsums[4];

    const int tid = threadIdx.x;
    const long long cell0 = (long long)blockIdx.x * 256;
    const long long cell  = cell0 + tid;
    const bool live = (cell < n_cells);

    const float* __restrict__ pblk = pred + cell0 * CH;
    const float* __restrict__ tblk = tgt  + cell0 * CH;
    const long long rem_f = (n_cells - cell0) * CH;   // valid floats in range
    const long long rem4  = rem_f / 4;
    const int lim = (rem4 < 1920) ? (int)rem4 : 1920; // 1920 float4s per tensor

    const float4* __restrict__ p4 = (const float4*)pblk;
    const float4* __restrict__ t4 = (const float4*)tblk;

    // ---------- single coalesced sweep: class inline, box -> LDS ----------
    float s_cls[8];
    int   s_cl[8];
    #pragma unroll
    for (int k = 0; k < 8; ++k) {
        const int v = tid + 256 * k;
        float clsv = 0.0f;
        int   cl   = 0;
        if (v < lim) {
            const float4 pv = p4[v];
            const float4 tv = t4[v];
            const int e = 4 * v;
            cl = e / 30;
            const int ch = e - 30 * cl;               // even, 0..28
            const float pe_[4] = {pv.x, pv.y, pv.z, pv.w};
            const float te_[4] = {tv.x, tv.y, tv.z, tv.w};
            #pragma unroll
            for (int j = 0; j < 4; ++j) {
                int chj = ch + j;
                const int wrap = (chj >= 30) ? 1 : 0; // only ch=28 wraps (j=2,3)
                chj -= 30 * wrap;
                const int cellj = cl + wrap;
                if (chj >= 10) {                      // class channel
                    const float d = pe_[j] - te_[j];
                    clsv += d * d;                    // class cell is always cl
                } else {                              // box/conf channel -> LDS
                    sp_box[cellj * PAD + chj] = pe_[j];
                    st_box[cellj * PAD + chj] = te_[j];
                    if (chj == 4)
                        s_obj[cellj] = (te_[j] > 0.0f) ? 1.0f : 0.0f;
                }
            }
        }
        s_cls[k] = clsv;
        s_cl[k]  = cl;
    }

    // scalar epilogue: rem_f % 4 == 2 possible (odd trailing cell count);
    // leftover elements are always ch 28/29 (class) of the block's last cell.
    float cls_extra = 0.0f;
    int   cl_extra  = 0;
    if (tid == 0 && (long long)lim * 4 < rem_f) {
        for (long long e2 = (long long)lim * 4; e2 < rem_f; ++e2) {
            const float d = pblk[e2] - tblk[e2];
            cls_extra += d * d;
        }
        cl_extra = (int)((rem_f - 1) / 30);
    }
    __syncthreads();

    // ---------- per-cell box / IoU / conf math from LDS ----------
    float acc = 0.0f;
    if (live) {
        const float* __restrict__ pb_ = sp_box + tid * PAD;
        const float* __restrict__ tb_ = st_box + tid * PAD;

        const float obj   = (tb_[4] > 0.0f) ? 1.0f : 0.0f;
        const float noobj = 1.0f - obj;

        const float d4 = pb_[4] - tb_[4];
        const float d9 = pb_[9] - tb_[9];
        const float l_noobj = d4 * d4 + d9 * d9;

        // target box 0 -> xyxy (matches reference op order)
        const float t_x0 = tb_[0] / SDIV - 0.5f * tb_[2];
        const float t_y0 = tb_[1] / SDIV - 0.5f * tb_[3];
        const float t_x1 = tb_[0] / SDIV + 0.5f * tb_[2];
        const float t_y1 = tb_[1] / SDIV + 0.5f * tb_[3];
        const float area_t = (t_x1 - t_x0) * (t_y1 - t_y0);

        float iou0, iou1;
        #pragma unroll
        for (int b = 0; b < 2; ++b) {
            const float* bx = pb_ + 5 * b;
            const float x0 = bx[0] / SDIV - 0.5f * bx[2];
            const float y0 = bx[1] / SDIV - 0.5f * bx[3];
            const float x1 = bx[0] / SDIV + 0.5f * bx[2];
            const float y1 = bx[1] / SDIV + 0.5f * bx[3];
            const float ltx = fmaxf(x0, t_x0);
            const float lty = fmaxf(y0, t_y0);
            const float rbx = fminf(x1, t_x1);
            const float rby = fminf(y1, t_y1);
            const float w = fmaxf(rbx - ltx, 0.0f);
            const float h = fmaxf(rby - lty, 0.0f);
            const float inter  = w * h;
            const float area_p = (x1 - x0) * (y1 - y0);
            const float uni = fmaxf(area_p + area_t - inter, 1e-10f);
            const float iou = inter / uni;
            if (b == 0) iou0 = iou; else iou1 = iou;
        }

        // jnp.argmax picks first on ties -> box1 only if strictly greater
        const int   bsel    = (iou1 > iou0) ? 1 : 0;
        const float max_iou = bsel ? iou1 : iou0;
        const float* pr = pb_ + 5 * bsel;
        const float* tr = tb_ + 5 * bsel;

        const float dx = pr[0] - tr[0];
        const float dy = pr[1] - tr[1];
        const float l_xy = dx * dx + dy * dy;
        const float dw = sqrtf(pr[2]) - sqrtf(tr[2]);
        const float dh = sqrtf(pr[3]) - sqrtf(tr[3]);
        const float l_wh = dw * dw + dh * dh;
        const float dc = pr[4] - max_iou;
        const float l_obj = dc * dc;

        acc = obj * (5.0f * (l_xy + l_wh) + l_obj) + 0.5f * noobj * l_noobj;
    }

    // ---------- weight deferred class partials by per-cell obj ----------
    #pragma unroll
    for (int k = 0; k < 8; ++k)
        acc += s_obj[s_cl[k]] * s_cls[k];
    if (cls_extra != 0.0f)
        acc += s_obj[cl_extra] * cls_extra;

    // ---- reduce: wave64 shuffle -> per-wave LDS -> per-block result ----
    float v = acc;
    #pragma unroll
    for (int off = 32; off > 0; off >>= 1)
        v += __shfl_down(v, off, 64);

    const int wave = tid >> 6;
    const int lane = tid & 63;
    if (lane == 0) wsums[wave] = v;
    __syncthreads();
    if (tid == 0) {
        const float sum = wsums[0] + wsums[1] + wsums[2] + wsums[3];
        if (USE_ATOMIC) atomicAdd(dst, sum * scale);
        else            dst[blockIdx.x] = sum;
    }
}

__global__ __launch_bounds__(256) void yolo_loss_pass2(
    const float* __restrict__ partials, float* __restrict__ out,
    int n_partials, float scale)
{
    __shared__ float wsums[4];
    const int tid = threadIdx.x;

    float v = 0.0f;
    for (int i = tid; i < n_partials; i += 256)
        v += partials[i];

    #pragma unroll
    for (int off = 32; off > 0; off >>= 1)
        v += __shfl_down(v, off, 64);

    const int wave = tid >> 6;
    const int lane = tid & 63;
    if (lane == 0) wsums[wave] = v;
    __syncthreads();
    if (tid == 0)
        out[0] = (wsums[0] + wsums[1] + wsums[2] + wsums[3]) * scale;
}

__global__ __launch_bounds__(64) void zero_out_kernel(float* out) {
    if (threadIdx.x == 0) out[0] = 0.0f;
}

extern "C" void kernel_launch(void* const* d_in, const int* in_sizes, int n_in,
                              void* d_out, int out_size, void* d_ws, size_t ws_size,
                              hipStream_t stream) {
    const float* pred = (const float*)d_in[0];
    const float* tgt  = (const float*)d_in[1];
    float* out = (float*)d_out;
    float* partials = (float*)d_ws;

    const long long total   = (long long)in_sizes[0];
    const long long n_cells = total / CH;          // bs*S*S
    const long long bs      = n_cells / 49;        // S*S = 49
    const float scale = 1.0f / (float)bs;

    const int grid = (int)((n_cells + 255) / 256);

    if (ws_size >= (size_t)grid * sizeof(float)) {
        // deterministic two-pass path
        yolo_loss_pass1<false><<<grid, 256, 0, stream>>>(pred, tgt, partials,
                                                         n_cells, scale);
        yolo_loss_pass2<<<1, 256, 0, stream>>>(partials, out, grid, scale);
    } else {
        // fallback: zero-init + one atomic per block
        zero_out_kernel<<<1, 64, 0, stream>>>(out);
        yolo_loss_pass1<true><<<grid, 256, 0, stream>>>(pred, tgt, out,
                                                        n_cells, scale);
    }
}

// Round 5
// 388.078 us; speedup vs baseline: 18128.1752x; 18128.1752x over previous
//
#include <hip/hip_runtime.h>

// YOLO-style loss: pred/target (bs, 7, 7, 30) fp32 -> scalar.
// S=7, B=2 boxes (5 ch each), C=20 classes. Memory-bound streaming reduction.
//
// v5 (resubmit; previous run died to an infra container failure, not a
// kernel verdict): cell-PAIR per thread, all-register, read-once float4.
//  - 2 cells = 60 floats = 240 B = 15 float4s, 16B-aligned (240%16==0).
//    Each thread loads 15+15 float4s at compile-time offsets into registers.
//    Channel->slot mapping is STATIC (v4's fatal flaw was data-dependent
//    per-element channel decode with divergent LDS scatter).
//  - Class-channel squared diffs consumed inline per slot; box/IoU math is
//    v2's exact arithmetic (absmax 0.0) on constant-indexed register arrays
//    with ?: selects (no runtime indexing -> no scratch).
//  - L1 line-txns: 15/cell vs v2's 30/cell (16B per lane-touch vs 8B).
//    ~24M txns / 256 CU / ~1 line/cy ~= 39 us of TCP work, under HBM floor.
//  - No LDS staging, no barriers except the final 16B reduce. Read-once
//    keeps v2's L3 residency (v3's double-read pushed FETCH 188->357MB).
// Pass 2: single block reduces per-block partials -> out[0]. Deterministic.
// Fallback (ws too small): zero-init + one atomicAdd per block.

#define CH 30
#define SDIV 7.0f

// Box/conf/IoU loss for one cell given its 10 box floats (ch 0..9) of pred
// and target, all constant-indexed. Returns obj flag via obj_out.
__device__ __forceinline__ float box_loss(const float p[10], const float t[10],
                                          float& obj_out)
{
    const float obj   = (t[4] > 0.0f) ? 1.0f : 0.0f;
    obj_out = obj;
    const float noobj = 1.0f - obj;

    const float d4 = p[4] - t[4];
    const float d9 = p[9] - t[9];
    const float l_noobj = d4 * d4 + d9 * d9;

    // target box 0 -> xyxy (matches reference op order)
    const float t_x0 = t[0] / SDIV - 0.5f * t[2];
    const float t_y0 = t[1] / SDIV - 0.5f * t[3];
    const float t_x1 = t[0] / SDIV + 0.5f * t[2];
    const float t_y1 = t[1] / SDIV + 0.5f * t[3];
    const float area_t = (t_x1 - t_x0) * (t_y1 - t_y0);

    float iou0, iou1;
    #pragma unroll
    for (int b = 0; b < 2; ++b) {
        const float bx0 = b ? p[5] : p[0];
        const float bx1 = b ? p[6] : p[1];
        const float bx2 = b ? p[7] : p[2];
        const float bx3 = b ? p[8] : p[3];
        const float x0 = bx0 / SDIV - 0.5f * bx2;
        const float y0 = bx1 / SDIV - 0.5f * bx3;
        const float x1 = bx0 / SDIV + 0.5f * bx2;
        const float y1 = bx1 / SDIV + 0.5f * bx3;
        const float ltx = fmaxf(x0, t_x0);
        const float lty = fmaxf(y0, t_y0);
        const float rbx = fminf(x1, t_x1);
        const float rby = fminf(y1, t_y1);
        const float w = fmaxf(rbx - ltx, 0.0f);
        const float h = fmaxf(rby - lty, 0.0f);
        const float inter  = w * h;
        const float area_p = (x1 - x0) * (y1 - y0);
        const float uni = fmaxf(area_p + area_t - inter, 1e-10f);
        const float iou = inter / uni;
        if (b == 0) iou0 = iou; else iou1 = iou;
    }

    // jnp.argmax picks first on ties -> box1 only if strictly greater
    const bool  bsel    = (iou1 > iou0);
    const float max_iou = bsel ? iou1 : iou0;

    const float prx = bsel ? p[5] : p[0];
    const float pry = bsel ? p[6] : p[1];
    const float prw = bsel ? p[7] : p[2];
    const float prh = bsel ? p[8] : p[3];
    const float prc = bsel ? p[9] : p[4];
    const float trx = bsel ? t[5] : t[0];
    const float try_ = bsel ? t[6] : t[1];
    const float trw = bsel ? t[7] : t[2];
    const float trh = bsel ? t[8] : t[3];

    const float dx = prx - trx;
    const float dy = pry - try_;
    const float l_xy = dx * dx + dy * dy;
    const float dw = sqrtf(prw) - sqrtf(trw);
    const float dh = sqrtf(prh) - sqrtf(trh);
    const float l_wh = dw * dw + dh * dh;
    const float dc = prc - max_iou;
    const float l_obj = dc * dc;

    return obj * (5.0f * (l_xy + l_wh) + l_obj) + 0.5f * noobj * l_noobj;
}

#define SQD(a, b) (((a) - (b)) * ((a) - (b)))

template <bool USE_ATOMIC>
__global__ __launch_bounds__(256) void yolo_loss_pass1(
    const float* __restrict__ pred, const float* __restrict__ tgt,
    float* __restrict__ dst, long long n_cells, float scale)
{
    __shared__ float wsums[4];

    const int tid = threadIdx.x;
    const long long pair  = (long long)blockIdx.x * 256 + tid;
    const long long cellA = 2 * pair;
    const long long cellB = cellA + 1;

    float acc = 0.0f;

    if (cellB < n_cells) {
        // ---- fast path: 15+15 float4 loads, all-register, static slots ----
        const float4* __restrict__ p4 = (const float4*)(pred + cellA * CH);
        const float4* __restrict__ t4 = (const float4*)(tgt  + cellA * CH);

        float4 P[15], T[15];
        #pragma unroll
        for (int i = 0; i < 15; ++i) { P[i] = p4[i]; T[i] = t4[i]; }

        // class sums (static slots). Cell A: ch10..29 = f2.zw, f3..f6, f7.xy
        float clsA = SQD(P[2].z, T[2].z) + SQD(P[2].w, T[2].w)
                   + SQD(P[7].x, T[7].x) + SQD(P[7].y, T[7].y);
        #pragma unroll
        for (int i = 3; i <= 6; ++i) {
            clsA += SQD(P[i].x, T[i].x) + SQD(P[i].y, T[i].y)
                  + SQD(P[i].z, T[i].z) + SQD(P[i].w, T[i].w);
        }
        // Cell B: ch10..29 = f10..f14
        float clsB = 0.0f;
        #pragma unroll
        for (int i = 10; i <= 14; ++i) {
            clsB += SQD(P[i].x, T[i].x) + SQD(P[i].y, T[i].y)
                  + SQD(P[i].z, T[i].z) + SQD(P[i].w, T[i].w);
        }

        // box floats (ch 0..9), static slots
        const float pA[10] = {P[0].x, P[0].y, P[0].z, P[0].w,
                              P[1].x, P[1].y, P[1].z, P[1].w,
                              P[2].x, P[2].y};
        const float tA[10] = {T[0].x, T[0].y, T[0].z, T[0].w,
                              T[1].x, T[1].y, T[1].z, T[1].w,
                              T[2].x, T[2].y};
        const float pB[10] = {P[7].z, P[7].w,
                              P[8].x, P[8].y, P[8].z, P[8].w,
                              P[9].x, P[9].y, P[9].z, P[9].w};
        const float tB[10] = {T[7].z, T[7].w,
                              T[8].x, T[8].y, T[8].z, T[8].w,
                              T[9].x, T[9].y, T[9].z, T[9].w};

        float objA, objB;
        acc  = box_loss(pA, tA, objA) + objA * clsA;
        acc += box_loss(pB, tB, objB) + objB * clsB;
    } else if (cellA < n_cells) {
        // ---- tail: single trailing cell (odd n_cells), scalar loads ----
        const float* __restrict__ p = pred + cellA * CH;
        const float* __restrict__ t = tgt  + cellA * CH;
        float pA[10], tA[10];
        #pragma unroll
        for (int c = 0; c < 10; ++c) { pA[c] = p[c]; tA[c] = t[c]; }
        float cls = 0.0f;
        #pragma unroll
        for (int c = 10; c < 30; ++c) cls += SQD(p[c], t[c]);
        float objA;
        acc = box_loss(pA, tA, objA) + objA * cls;
    }

    // ---- reduce: wave64 shuffle -> per-wave LDS -> per-block result ----
    float v = acc;
    #pragma unroll
    for (int off = 32; off > 0; off >>= 1)
        v += __shfl_down(v, off, 64);

    const int wave = tid >> 6;
    const int lane = tid & 63;
    if (lane == 0) wsums[wave] = v;
    __syncthreads();
    if (tid == 0) {
        const float sum = wsums[0] + wsums[1] + wsums[2] + wsums[3];
        if (USE_ATOMIC) atomicAdd(dst, sum * scale);
        else            dst[blockIdx.x] = sum;
    }
}

__global__ __launch_bounds__(256) void yolo_loss_pass2(
    const float* __restrict__ partials, float* __restrict__ out,
    int n_partials, float scale)
{
    __shared__ float wsums[4];
    const int tid = threadIdx.x;

    float v = 0.0f;
    for (int i = tid; i < n_partials; i += 256)
        v += partials[i];

    #pragma unroll
    for (int off = 32; off > 0; off >>= 1)
        v += __shfl_down(v, off, 64);

    const int wave = tid >> 6;
    const int lane = tid & 63;
    if (lane == 0) wsums[wave] = v;
    __syncthreads();
    if (tid == 0)
        out[0] = (wsums[0] + wsums[1] + wsums[2] + wsums[3]) * scale;
}

__global__ __launch_bounds__(64) void zero_out_kernel(float* out) {
    if (threadIdx.x == 0) out[0] = 0.0f;
}

extern "C" void kernel_launch(void* const* d_in, const int* in_sizes, int n_in,
                              void* d_out, int out_size, void* d_ws, size_t ws_size,
                              hipStream_t stream) {
    const float* pred = (const float*)d_in[0];
    const float* tgt  = (const float*)d_in[1];
    float* out = (float*)d_out;
    float* partials = (float*)d_ws;

    const long long total   = (long long)in_sizes[0];
    const long long n_cells = total / CH;          // bs*S*S
    const long long bs      = n_cells / 49;        // S*S = 49
    const float scale = 1.0f / (float)bs;

    // one thread per cell-PAIR; block covers 512 cells
    const int grid = (int)((n_cells + 511) / 512);

    if (ws_size >= (size_t)grid * sizeof(float)) {
        // deterministic two-pass path
        yolo_loss_pass1<false><<<grid, 256, 0, stream>>>(pred, tgt, partials,
                                                         n_cells, scale);
        yolo_loss_pass2<<<1, 256, 0, stream>>>(partials, out, grid, scale);
    } else {
        // fallback: zero-init + one atomic per block
        zero_out_kernel<<<1, 64, 0, stream>>>(out);
        yolo_loss_pass1<true><<<grid, 256, 0, stream>>>(pred, tgt, out,
                                                        n_cells, scale);
    }
}